// Round 15
// baseline (474.872 us; speedup 1.0000x reference)
//
#include <hip/hip_runtime.h>
#include <hip/hip_fp16.h>

#define NG 50000
#define NC 100000
#define DIN 128
#define D 64
#define EGG 800000
#define ECG 1600000
#define ECC 1600000
#define LN_EPS 1e-5f

#define SCAN_N (2 * NG + NC)            // 200000 keys: gg dst | cg dst | cc dst
#define E_ALL (EGG + ECG + ECC)         // 4,000,000 edges
#define NBKT 196                        // buckets of 1024 keys
#define NBLK 512                        // blocks in R1/R3
#define EPB ((E_ALL + NBLK - 1) / NBLK) // edges per block = 7813

typedef _Float16 f16x8 __attribute__((ext_vector_type(8)));
typedef float f32x4 __attribute__((ext_vector_type(4)));

__device__ __forceinline__ float wave_sum64(float v) {
#pragma unroll
  for (int off = 32; off > 0; off >>= 1) v += __shfl_xor(v, off);
  return v;
}

// ---- pair-edge scalar-indexed fp16 CSR gather -------------------------------
// e0/e1 wave-uniform (SGPR). lane = h*32+m: h = edge parity, m = dim pair.
// One half2 load covers 2 dims of 1 of 2 edges -> 16 rows in flight per wave.
__device__ __forceinline__ float csr_gather_s2(
    const int* __restrict__ src, const float* __restrict__ nrm,
    const __half* __restrict__ tab, int e0, int e1, int lane) {
  int h = lane >> 5;
  int m = lane & 31;
  float ax0 = 0.f, ax1 = 0.f, ax2 = 0.f, ax3 = 0.f;
  float ay0 = 0.f, ay1 = 0.f, ay2 = 0.f, ay3 = 0.f;
  for (int e = e0; e < e1; e += 16) {
#pragma unroll
    for (int p = 0; p < 8; ++p) {
      int i0 = e + 2 * p;
      int se = src[i0];          // SGPR (sequential s_load)
      int so = src[i0 + 1];      // SGPR
      int s = h ? so : se;       // v_cndmask
      bool valid = (i0 + h) < e1;
      float w;
      if (nrm) {
        float we = nrm[i0], wo = nrm[i0 + 1];
        w = h ? wo : we;
      } else {
        w = 1.0f;
      }
      w = valid ? w : 0.0f;
      s = valid ? s : 0;
      __half2 v = *(const __half2*)(tab + (size_t)s * D + 2 * m);
      float vl = __low2float(v), vh = __high2float(v);
      switch (p & 3) {
        case 0: ax0 = fmaf(w, vl, ax0); ay0 = fmaf(w, vh, ay0); break;
        case 1: ax1 = fmaf(w, vl, ax1); ay1 = fmaf(w, vh, ay1); break;
        case 2: ax2 = fmaf(w, vl, ax2); ay2 = fmaf(w, vh, ay2); break;
        default: ax3 = fmaf(w, vl, ax3); ay3 = fmaf(w, vh, ay3); break;
      }
    }
  }
  float ax = (ax0 + ax1) + (ax2 + ax3);
  float ay = (ay0 + ay1) + (ay2 + ay3);
  ax += __shfl_xor(ax, 32);   // combine even/odd edge halves
  ay += __shfl_xor(ay, 32);
  // redistribute pair layout -> lane=dim
  float ev = __shfl(ax, lane >> 1);
  float od = __shfl(ay, lane >> 1);
  return (lane & 1) ? od : ev;
}

// B-fragment loader: W fp32 [64][64] -> f16x8 frag (col c, k = kbase..kbase+7)
__device__ __forceinline__ f16x8 ldB(const float* __restrict__ W, int kbase, int c) {
  f16x8 v;
#pragma unroll
  for (int j = 0; j < 8; ++j) v[j] = (_Float16)W[(kbase + j) * 64 + c];
  return v;
}

// ---------------- dense input FC via MFMA -----------------------------------
__global__ __launch_bounds__(256) void fc_in_mfma_kernel(
    const float* __restrict__ x, const float* __restrict__ W,
    const float* __restrict__ b, const float* __restrict__ s,
    const float* __restrict__ beta, __half* __restrict__ y, int n) {
  int wid = (int)(((size_t)blockIdx.x * blockDim.x + threadIdx.x) >> 6);
  int lane = threadIdx.x & 63;
  int r0 = wid * 16;
  if (r0 >= n) return;
  int lo = lane & 15;
  int hi = lane >> 4;

  f16x8 bf[4][4];
#pragma unroll
  for (int kk = 0; kk < 4; ++kk) {
    int kbase = kk * 32 + hi * 8;
#pragma unroll
    for (int t = 0; t < 4; ++t) bf[kk][t] = ldB(W, kbase, t * 16 + lo);
  }

  f32x4 acc[4];
#pragma unroll
  for (int t = 0; t < 4; ++t) acc[t] = (f32x4){0.f, 0.f, 0.f, 0.f};

  const float* xr = x + (size_t)(r0 + lo) * DIN;
#pragma unroll
  for (int kk = 0; kk < 4; ++kk) {
    int kbase = kk * 32 + hi * 8;
    float4 xa = *(const float4*)(xr + kbase);
    float4 xb = *(const float4*)(xr + kbase + 4);
    f16x8 af;
    af[0] = (_Float16)xa.x; af[1] = (_Float16)xa.y;
    af[2] = (_Float16)xa.z; af[3] = (_Float16)xa.w;
    af[4] = (_Float16)xb.x; af[5] = (_Float16)xb.y;
    af[6] = (_Float16)xb.z; af[7] = (_Float16)xb.w;
#pragma unroll
    for (int t = 0; t < 4; ++t)
      acc[t] = __builtin_amdgcn_mfma_f32_16x16x32_f16(af, bf[kk][t], acc[t], 0, 0, 0);
  }

  float bc[4], lsv[4], lbv[4];
#pragma unroll
  for (int t = 0; t < 4; ++t) {
    int c = t * 16 + lo;
    bc[t] = b[c]; lsv[t] = s[c]; lbv[t] = beta[c];
  }
#pragma unroll
  for (int reg = 0; reg < 4; ++reg) {
    float v[4];
    float s1 = 0.0f;
#pragma unroll
    for (int t = 0; t < 4; ++t) { v[t] = acc[t][reg] + bc[t]; s1 += v[t]; }
#pragma unroll
    for (int off = 1; off < 16; off <<= 1) s1 += __shfl_xor(s1, off);
    float m = s1 * (1.0f / 64.0f);
    float s2 = 0.0f;
#pragma unroll
    for (int t = 0; t < 4; ++t) { float d = v[t] - m; s2 += d * d; }
#pragma unroll
    for (int off = 1; off < 16; off <<= 1) s2 += __shfl_xor(s2, off);
    float rinv = rsqrtf(s2 * (1.0f / 64.0f) + LN_EPS);
    int r = r0 + hi * 4 + reg;
#pragma unroll
    for (int t = 0; t < 4; ++t) {
      float o = (v[t] - m) * rinv * lsv[t] + lbv[t];
      y[(size_t)r * D + t * 16 + lo] = __float2half(fmaxf(o, 0.0f));
    }
  }
}

// =============== atomic-free CSR build: 2-level counting sort ===============
__global__ __launch_bounds__(256) void r1_hist_kernel(
    const int* __restrict__ ei_gg, const int* __restrict__ ei_cg,
    const int* __restrict__ ei_cc, int* __restrict__ bhist,
    int* __restrict__ btot) {
  __shared__ int hist[256];
  int t = threadIdx.x;
  int k = blockIdx.x;
  hist[t] = 0;
  __syncthreads();
  int base = k * EPB;
  for (int i = t; i < EPB; i += 256) {
    int e = base + i;
    if (e >= E_ALL) break;
    int key;
    if (e < EGG) key = ei_gg[EGG + e];
    else if (e < EGG + ECG) key = NG + ei_cg[ECG + (e - EGG)];
    else key = 2 * NG + ei_cc[ECC + (e - EGG - ECG)];
    atomicAdd(&hist[key >> 10], 1);
  }
  __syncthreads();
  if (t < NBKT) {
    bhist[t * NBLK + k] = hist[t];
    atomicAdd(&btot[t], hist[t]);
  }
}

__global__ __launch_bounds__(256) void r2b_kernel(
    const int* __restrict__ btot, int* __restrict__ bbase,
    int* __restrict__ S) {
  __shared__ int sh[256];
  int t = threadIdx.x;
  int v = (t < NBKT) ? btot[t] : 0;
  sh[t] = v;
  __syncthreads();
#pragma unroll
  for (int off = 1; off < 256; off <<= 1) {
    int u = (t >= off) ? sh[t - off] : 0;
    __syncthreads();
    sh[t] += u;
    __syncthreads();
  }
  if (t < NBKT) bbase[t] = sh[t] - v;
  if (t == 255) { bbase[NBKT] = sh[255]; S[SCAN_N] = sh[255]; }
}

__global__ __launch_bounds__(512) void r2c_kernel(
    const int* __restrict__ bhist, const int* __restrict__ bbase,
    int* __restrict__ base) {
  int b = blockIdx.x;
  int t = threadIdx.x;
  int lane = t & 63, wv = t >> 6;
  int v = bhist[b * NBLK + t];
  int sc = v;
#pragma unroll
  for (int off = 1; off < 64; off <<= 1) {
    int u = __shfl_up(sc, off);
    if (lane >= off) sc += u;
  }
  __shared__ int ws[8];
  if (lane == 63) ws[wv] = sc;
  __syncthreads();
  int wb = 0;
  for (int i = 0; i < wv; ++i) wb += ws[i];
  base[b * NBLK + t] = bbase[b] + wb + sc - v;
}

__global__ __launch_bounds__(256) void r3_scatter_kernel(
    const int* __restrict__ ei_gg, const float* __restrict__ ew_gg,
    const int* __restrict__ ei_cg, const int* __restrict__ ei_cc,
    const int* __restrict__ base, int* __restrict__ ssort,
    float* __restrict__ wsort) {
  __shared__ int cur[256];
  int t = threadIdx.x;
  int k = blockIdx.x;
  if (t < NBKT) cur[t] = base[t * NBLK + k];
  __syncthreads();
  int bb = k * EPB;
  for (int i = t; i < EPB; i += 256) {
    int e = bb + i;
    if (e >= E_ALL) break;
    int key, s; float w = 0.0f; bool isg = false;
    if (e < EGG) {
      key = ei_gg[EGG + e]; s = ei_gg[e]; w = ew_gg[e]; isg = true;
    } else if (e < EGG + ECG) {
      int q = e - EGG; key = NG + ei_cg[ECG + q]; s = ei_cg[q];
    } else {
      int q = e - EGG - ECG; key = 2 * NG + ei_cc[ECC + q]; s = ei_cc[q];
    }
    int p = atomicAdd(&cur[key >> 10], 1);   // LDS atomic
    ssort[p] = ((key & 1023) << 17) | s;     // src < 2^17
    if (isg) wsort[p] = w;
  }
}

__global__ __launch_bounds__(1024) void r4_sort_kernel(
    const int* __restrict__ ssort, const float* __restrict__ wsort,
    const int* __restrict__ bbase, int* __restrict__ S,
    int* __restrict__ srcbuf, float* __restrict__ ewp) {
  int b = blockIdx.x;
  int t = threadIdx.x;
  int e0 = bbase[b], e1 = bbase[b + 1];
  int kbase = b << 10;
  __shared__ int hist[1024];
  __shared__ int sh[1024];
  __shared__ int cur[1024];
  hist[t] = 0;
  __syncthreads();
  for (int e = e0 + t; e < e1; e += 1024)
    atomicAdd(&hist[((unsigned)ssort[e]) >> 17], 1);
  __syncthreads();
  int c = hist[t];
  sh[t] = c;
  __syncthreads();
#pragma unroll
  for (int off = 1; off < 1024; off <<= 1) {
    int u = (t >= off) ? sh[t - off] : 0;
    __syncthreads();
    sh[t] += u;
    __syncthreads();
  }
  int ex = e0 + sh[t] - c;
  int key = kbase + t;
  if (key < SCAN_N) S[key] = ex;
  cur[t] = ex;
  __syncthreads();
  for (int e = e0 + t; e < e1; e += 1024) {
    int rec = ssort[e];
    int lk = ((unsigned)rec) >> 17;
    int p = atomicAdd(&cur[lk], 1);
    srcbuf[p] = rec & 0x1FFFF;
    if (kbase + lk < NG) ewp[p] = wsort[e];
  }
}

__global__ __launch_bounds__(256) void deg_kernel(
    const int* __restrict__ S, const float* __restrict__ ewp,
    float* __restrict__ dinv) {
  int i = (int)(((size_t)blockIdx.x * blockDim.x + threadIdx.x) >> 6);
  int lane = threadIdx.x & 63;
  if (i >= NG) return;
  int e0 = S[i], e1 = S[i + 1];
  float s = 0.0f;
  for (int e = e0 + lane; e < e1; e += 64) s += ewp[e];
  s = wave_sum64(s);
  if (lane == 0) dinv[i] = rsqrtf(s + 1.0f);
}

__global__ __launch_bounds__(256) void nrm_kernel(
    const int* __restrict__ S, const int* __restrict__ srcbuf,
    const float* __restrict__ ewp, const float* __restrict__ dinv,
    float* __restrict__ nrm) {
  int i = (int)(((size_t)blockIdx.x * blockDim.x + threadIdx.x) >> 6);
  int lane = threadIdx.x & 63;
  if (i >= NG) return;
  float di = dinv[i];
  int e0 = S[i], e1 = S[i + 1];
  for (int e = e0 + lane; e < e1; e += 64)
    nrm[e] = dinv[srcbuf[e]] * ewp[e] * di;
}

// ---------------- fused glom layer: 16 rows/block, MFMA epilogue ------------
// 16 waves gather one row each into LDS (fp16); wave 0 then does the two
// 16x64 @ 64x64 matmuls on matrix cores + bias/relu/combine/LN/store.
__global__ __launch_bounds__(1024) void glom_layer_kernel(
    const int* __restrict__ rp_gg, const int* __restrict__ rp_cg,
    const int* __restrict__ srcbuf, const float* __restrict__ nrm_gg,
    const __half* __restrict__ xg_old, const __half* __restrict__ xc_old,
    const float* __restrict__ dinv,
    const float* __restrict__ W_gcn, const float* __restrict__ b_gcn,
    const float* __restrict__ eps_cg, const float* __restrict__ W_cg,
    const float* __restrict__ b_cg,
    const float* __restrict__ ls, const float* __restrict__ lb,
    __half* __restrict__ xg_new) {
  __shared__ __align__(16) _Float16 A1[16][72];  // accG rows (+8 pad: 2-way banks)
  __shared__ __align__(16) _Float16 A2[16][72];  // h rows
  int wv = threadIdx.x >> 6;
  int lane = threadIdx.x & 63;
  int iu = __builtin_amdgcn_readfirstlane(blockIdx.x * 16 + wv);

  int ge0 = __builtin_amdgcn_readfirstlane(rp_gg[iu]);
  int ge1 = __builtin_amdgcn_readfirstlane(rp_gg[iu + 1]);
  int fe0 = __builtin_amdgcn_readfirstlane(rp_cg[iu]);
  int fe1 = __builtin_amdgcn_readfirstlane(rp_cg[iu + 1]);
  float self = __half2float(xg_old[(size_t)iu * D + lane]);
  float di = dinv[iu];
  float accG = di * di * self
             + csr_gather_s2(srcbuf, nrm_gg, xg_old, ge0, ge1, lane);
  float accC = csr_gather_s2(srcbuf, nullptr, xc_old, fe0, fe1, lane);
  float h = (1.0f + eps_cg[0]) * self + accC;
  A1[wv][lane] = (_Float16)accG;
  A2[wv][lane] = (_Float16)h;
  __syncthreads();
  if (wv != 0) return;

  // ---- wave 0: MFMA epilogue ----
  int lo = lane & 15;
  int hi = lane >> 4;
  f16x8 a1[2], a2[2];
#pragma unroll
  for (int kk = 0; kk < 2; ++kk) {
    a1[kk] = *(const f16x8*)&A1[lo][kk * 32 + hi * 8];
    a2[kk] = *(const f16x8*)&A2[lo][kk * 32 + hi * 8];
  }
  f32x4 c1[4], c2[4];
#pragma unroll
  for (int t = 0; t < 4; ++t) {
    int c = t * 16 + lo;
    f32x4 acc = (f32x4){0.f, 0.f, 0.f, 0.f};
#pragma unroll
    for (int kk = 0; kk < 2; ++kk)
      acc = __builtin_amdgcn_mfma_f32_16x16x32_f16(a1[kk], ldB(W_gcn, kk * 32 + hi * 8, c), acc, 0, 0, 0);
    c1[t] = acc;
    acc = (f32x4){0.f, 0.f, 0.f, 0.f};
#pragma unroll
    for (int kk = 0; kk < 2; ++kk)
      acc = __builtin_amdgcn_mfma_f32_16x16x32_f16(a2[kk], ldB(W_cg, kk * 32 + hi * 8, c), acc, 0, 0, 0);
    c2[t] = acc;
  }
  float bc1[4], bc2[4], lsv[4], lbv[4];
#pragma unroll
  for (int t = 0; t < 4; ++t) {
    int c = t * 16 + lo;
    bc1[t] = b_gcn[c]; bc2[t] = b_cg[c]; lsv[t] = ls[c]; lbv[t] = lb[c];
  }
#pragma unroll
  for (int reg = 0; reg < 4; ++reg) {
    float v[4];
    float s1 = 0.0f;
#pragma unroll
    for (int t = 0; t < 4; ++t) {
      v[t] = (c1[t][reg] + bc1[t]) + fmaxf(c2[t][reg] + bc2[t], 0.0f);
      s1 += v[t];
    }
#pragma unroll
    for (int off = 1; off < 16; off <<= 1) s1 += __shfl_xor(s1, off);
    float m = s1 * (1.0f / 64.0f);
    float s2 = 0.0f;
#pragma unroll
    for (int t = 0; t < 4; ++t) { float d = v[t] - m; s2 += d * d; }
#pragma unroll
    for (int off = 1; off < 16; off <<= 1) s2 += __shfl_xor(s2, off);
    float rinv = rsqrtf(s2 * (1.0f / 64.0f) + LN_EPS);
    int r = blockIdx.x * 16 + hi * 4 + reg;
#pragma unroll
    for (int t = 0; t < 4; ++t) {
      float o = (v[t] - m) * rinv * lsv[t] + lbv[t];
      xg_new[(size_t)r * D + t * 16 + lo] = __float2half(fmaxf(o, 0.0f));
    }
  }
}

// ---------------- fused cell layer: 16 rows/block, MFMA epilogue ------------
__global__ __launch_bounds__(1024) void cell_layer_kernel(
    const int* __restrict__ rp_cc, const int* __restrict__ srcbuf,
    const __half* __restrict__ xc_old,
    const float* __restrict__ eps_cc, const float* __restrict__ W_cc,
    const float* __restrict__ b_cc,
    const float* __restrict__ ls, const float* __restrict__ lb,
    __half* __restrict__ xc_new) {
  __shared__ __align__(16) _Float16 A2[16][72];
  int wv = threadIdx.x >> 6;
  int lane = threadIdx.x & 63;
  int iu = __builtin_amdgcn_readfirstlane(blockIdx.x * 16 + wv);

  int e0 = __builtin_amdgcn_readfirstlane(rp_cc[iu]);
  int e1 = __builtin_amdgcn_readfirstlane(rp_cc[iu + 1]);
  float self = __half2float(xc_old[(size_t)iu * D + lane]);
  float acc = csr_gather_s2(srcbuf, nullptr, xc_old, e0, e1, lane);
  float h = (1.0f + eps_cc[0]) * self + acc;
  A2[wv][lane] = (_Float16)h;
  __syncthreads();
  if (wv != 0) return;

  int lo = lane & 15;
  int hi = lane >> 4;
  f16x8 a2[2];
#pragma unroll
  for (int kk = 0; kk < 2; ++kk)
    a2[kk] = *(const f16x8*)&A2[lo][kk * 32 + hi * 8];
  f32x4 c2[4];
#pragma unroll
  for (int t = 0; t < 4; ++t) {
    int c = t * 16 + lo;
    f32x4 a = (f32x4){0.f, 0.f, 0.f, 0.f};
#pragma unroll
    for (int kk = 0; kk < 2; ++kk)
      a = __builtin_amdgcn_mfma_f32_16x16x32_f16(a2[kk], ldB(W_cc, kk * 32 + hi * 8, c), a, 0, 0, 0);
    c2[t] = a;
  }
  float bc2[4], lsv[4], lbv[4];
#pragma unroll
  for (int t = 0; t < 4; ++t) {
    int c = t * 16 + lo;
    bc2[t] = b_cc[c]; lsv[t] = ls[c]; lbv[t] = lb[c];
  }
#pragma unroll
  for (int reg = 0; reg < 4; ++reg) {
    float v[4];
    float s1 = 0.0f;
#pragma unroll
    for (int t = 0; t < 4; ++t) {
      v[t] = fmaxf(c2[t][reg] + bc2[t], 0.0f);
      s1 += v[t];
    }
#pragma unroll
    for (int off = 1; off < 16; off <<= 1) s1 += __shfl_xor(s1, off);
    float m = s1 * (1.0f / 64.0f);
    float s2 = 0.0f;
#pragma unroll
    for (int t = 0; t < 4; ++t) { float d = v[t] - m; s2 += d * d; }
#pragma unroll
    for (int off = 1; off < 16; off <<= 1) s2 += __shfl_xor(s2, off);
    float rinv = rsqrtf(s2 * (1.0f / 64.0f) + LN_EPS);
    int r = blockIdx.x * 16 + hi * 4 + reg;
#pragma unroll
    for (int t = 0; t < 4; ++t) {
      float o = (v[t] - m) * rinv * lsv[t] + lbv[t];
      xc_new[(size_t)r * D + t * 16 + lo] = __float2half(fmaxf(o, 0.0f));
    }
  }
}

// ---------------- output head: wave per row --------------------------------
__global__ __launch_bounds__(256) void out_kernel(
    const __half* __restrict__ xg, const float* __restrict__ W,
    const float* __restrict__ b, float* __restrict__ out, int n) {
  int wid = (int)(((size_t)blockIdx.x * blockDim.x + threadIdx.x) >> 6);
  int lane = threadIdx.x & 63;
  if (wid >= n) return;
  float v = __half2float(xg[(size_t)wid * D + lane]);
  float a0 = wave_sum64(v * W[lane * 3 + 0]) + b[0];
  float a1 = wave_sum64(v * W[lane * 3 + 1]) + b[1];
  float a2 = wave_sum64(v * W[lane * 3 + 2]) + b[2];
  float m = fmaxf(a0, fmaxf(a1, a2));
  float e0 = expf(a0 - m), e1 = expf(a1 - m), e2 = expf(a2 - m);
  float inv = 1.0f / (e0 + e1 + e2);
  if (lane == 0) {
    out[(size_t)wid * 3 + 0] = e0 * inv;
    out[(size_t)wid * 3 + 1] = e1 * inv;
    out[(size_t)wid * 3 + 2] = e2 * inv;
  }
}

extern "C" void kernel_launch(void* const* d_in, const int* in_sizes, int n_in,
                              void* d_out, int out_size, void* d_ws, size_t ws_size,
                              hipStream_t stream) {
  const float* x_glom = (const float*)d_in[0];
  const float* x_cell = (const float*)d_in[1];
  const int*   ei_gg  = (const int*)d_in[2];
  const float* ew_gg  = (const float*)d_in[3];
  const int*   ei_cg  = (const int*)d_in[4];
  const int*   ei_cc  = (const int*)d_in[5];
  const float* W_in_g = (const float*)d_in[6];
  const float* b_in_g = (const float*)d_in[7];
  const float* lnig_s = (const float*)d_in[8];
  const float* lnig_b = (const float*)d_in[9];
  const float* W_in_c = (const float*)d_in[10];
  const float* b_in_c = (const float*)d_in[11];
  const float* lnic_s = (const float*)d_in[12];
  const float* lnic_b = (const float*)d_in[13];
  const float* W_outp = (const float*)d_in[34];
  const float* b_outp = (const float*)d_in[35];

  // ---- workspace layout ----
  char* P = (char*)d_ws;
  __half* xg0 = (__half*)P;                    P += (size_t)NG * D * 2;
  __half* xg1 = (__half*)P;                    P += (size_t)NG * D * 2;
  __half* xc0 = (__half*)P;                    P += (size_t)NC * D * 2;
  __half* xc1 = (__half*)P;                    P += (size_t)NC * D * 2;
  float* dinv = (float*)P;                     P += (size_t)NG * 4;
  float* nrm  = (float*)P;                     P += (size_t)EGG * 4;
  int* S      = (int*)P;                       P += (size_t)(SCAN_N + 1) * 4;
  int* srcbuf = (int*)P;                       P += (size_t)E_ALL * 4;
  int* bhist  = (int*)P;                       P += (size_t)NBKT * NBLK * 4;
  int* base   = (int*)P;                       P += (size_t)NBKT * NBLK * 4;
  int* btot   = (int*)P;                       P += (size_t)NBKT * 4;
  int* bbase  = (int*)P;                       P += (size_t)(NBKT + 1) * 4;
  // transients over the feature-table region (dead before fc_in writes it)
  int* ssort   = (int*)d_ws;
  float* wsort = (float*)(ssort + E_ALL);
  float* ewp   = wsort + EGG;

  dim3 blk(256);
  auto wgrid = [](long long waves) { return dim3((unsigned)((waves + 3) / 4)); };

  // ---- CSR build: atomic-free two-level counting sort ----
  hipMemsetAsync(btot, 0, NBKT * sizeof(int), stream);
  r1_hist_kernel<<<dim3(NBLK), blk, 0, stream>>>(ei_gg, ei_cg, ei_cc, bhist, btot);
  r2b_kernel<<<dim3(1), dim3(256), 0, stream>>>(btot, bbase, S);
  r2c_kernel<<<dim3(NBKT), dim3(512), 0, stream>>>(bhist, bbase, base);
  r3_scatter_kernel<<<dim3(NBLK), blk, 0, stream>>>(
      ei_gg, ew_gg, ei_cg, ei_cc, base, ssort, wsort);
  r4_sort_kernel<<<dim3(NBKT), dim3(1024), 0, stream>>>(
      ssort, wsort, bbase, S, srcbuf, ewp);
  deg_kernel<<<wgrid(NG), blk, 0, stream>>>(S, ewp, dinv);
  nrm_kernel<<<wgrid(NG), blk, 0, stream>>>(S, srcbuf, ewp, dinv, nrm);

  // ---- input FCs via MFMA (overwrite the transient ssort/wsort/ewp region) --
  fc_in_mfma_kernel<<<wgrid(NG / 16), blk, 0, stream>>>(
      x_glom, W_in_g, b_in_g, lnig_s, lnig_b, xg0, NG);
  fc_in_mfma_kernel<<<wgrid(NC / 16), blk, 0, stream>>>(
      x_cell, W_in_c, b_in_c, lnic_s, lnic_b, xc0, NC);

  // ---- two hetero MP layers (16 rows/block, MFMA epilogue) ----
  const int* rp_gg = S;
  const int* rp_cg = S + NG;
  const int* rp_cc = S + 2 * NG;
  __half* xg_cur = xg0; __half* xg_nxt = xg1;
  __half* xc_cur = xc0; __half* xc_nxt = xc1;
  for (int l = 0; l < 2; ++l) {
    const float* const* p = (const float* const*)(d_in + 14 + 10 * l);
    const float* W_gcn = p[0]; const float* b_gcn = p[1];
    const float* eps_cg = p[2]; const float* W_cg = p[3]; const float* b_cg = p[4];
    const float* eps_cc = p[5]; const float* W_cc = p[6]; const float* b_cc = p[7];
    const float* ln_s = p[8]; const float* ln_b = p[9];

    glom_layer_kernel<<<dim3(NG / 16), dim3(1024), 0, stream>>>(
        rp_gg, rp_cg, srcbuf, nrm, xg_cur, xc_cur, dinv,
        W_gcn, b_gcn, eps_cg, W_cg, b_cg, ln_s, ln_b, xg_nxt);
    cell_layer_kernel<<<dim3(NC / 16), dim3(1024), 0, stream>>>(
        rp_cc, srcbuf, xc_cur, eps_cc, W_cc, b_cc, ln_s, ln_b, xc_nxt);

    __half* t;
    t = xg_cur; xg_cur = xg_nxt; xg_nxt = t;
    t = xc_cur; xc_cur = xc_nxt; xc_nxt = t;
  }

  out_kernel<<<wgrid(NG), blk, 0, stream>>>(xg_cur, W_outp, b_outp, (float*)d_out, NG);
}

// Round 16
// 457.592 us; speedup vs baseline: 1.0378x; 1.0378x over previous
//
#include <hip/hip_runtime.h>
#include <hip/hip_fp16.h>

#define NG 50000
#define NC 100000
#define DIN 128
#define D 64
#define EGG 800000
#define ECG 1600000
#define ECC 1600000
#define LN_EPS 1e-5f

#define SCAN_N (2 * NG + NC)            // 200000 keys: gg dst | cg dst | cc dst
#define E_ALL (EGG + ECG + ECC)         // 4,000,000 edges
#define NBKT 196                        // buckets of 1024 keys
#define NBLK 512                        // blocks in R1/R3
#define EPB 7816                        // edges per block (4-aligned; 512*7816 >= E_ALL)

typedef _Float16 f16x8 __attribute__((ext_vector_type(8)));
typedef float f32x4 __attribute__((ext_vector_type(4)));

__device__ __forceinline__ float wave_sum64(float v) {
#pragma unroll
  for (int off = 32; off > 0; off >>= 1) v += __shfl_xor(v, off);
  return v;
}

// ---- pair-edge scalar-indexed fp16 CSR gather -------------------------------
__device__ __forceinline__ float csr_gather_s2(
    const int* __restrict__ src, const float* __restrict__ nrm,
    const __half* __restrict__ tab, int e0, int e1, int lane) {
  int h = lane >> 5;
  int m = lane & 31;
  float ax0 = 0.f, ax1 = 0.f, ax2 = 0.f, ax3 = 0.f;
  float ay0 = 0.f, ay1 = 0.f, ay2 = 0.f, ay3 = 0.f;
  for (int e = e0; e < e1; e += 16) {
#pragma unroll
    for (int p = 0; p < 8; ++p) {
      int i0 = e + 2 * p;
      int se = src[i0];
      int so = src[i0 + 1];
      int s = h ? so : se;
      bool valid = (i0 + h) < e1;
      float w;
      if (nrm) {
        float we = nrm[i0], wo = nrm[i0 + 1];
        w = h ? wo : we;
      } else {
        w = 1.0f;
      }
      w = valid ? w : 0.0f;
      s = valid ? s : 0;
      __half2 v = *(const __half2*)(tab + (size_t)s * D + 2 * m);
      float vl = __low2float(v), vh = __high2float(v);
      switch (p & 3) {
        case 0: ax0 = fmaf(w, vl, ax0); ay0 = fmaf(w, vh, ay0); break;
        case 1: ax1 = fmaf(w, vl, ax1); ay1 = fmaf(w, vh, ay1); break;
        case 2: ax2 = fmaf(w, vl, ax2); ay2 = fmaf(w, vh, ay2); break;
        default: ax3 = fmaf(w, vl, ax3); ay3 = fmaf(w, vh, ay3); break;
      }
    }
  }
  float ax = (ax0 + ax1) + (ax2 + ax3);
  float ay = (ay0 + ay1) + (ay2 + ay3);
  ax += __shfl_xor(ax, 32);
  ay += __shfl_xor(ay, 32);
  float ev = __shfl(ax, lane >> 1);
  float od = __shfl(ay, lane >> 1);
  return (lane & 1) ? od : ev;
}

// B-fragment loader: W fp32 [64][64] -> f16x8 frag (col c, k = kbase..kbase+7)
__device__ __forceinline__ f16x8 ldB(const float* __restrict__ W, int kbase, int c) {
  f16x8 v;
#pragma unroll
  for (int j = 0; j < 8; ++j) v[j] = (_Float16)W[(kbase + j) * 64 + c];
  return v;
}

// ---------------- dense input FC via MFMA -----------------------------------
__global__ __launch_bounds__(256) void fc_in_mfma_kernel(
    const float* __restrict__ x, const float* __restrict__ W,
    const float* __restrict__ b, const float* __restrict__ s,
    const float* __restrict__ beta, __half* __restrict__ y, int n) {
  int wid = (int)(((size_t)blockIdx.x * blockDim.x + threadIdx.x) >> 6);
  int lane = threadIdx.x & 63;
  int r0 = wid * 16;
  if (r0 >= n) return;
  int lo = lane & 15;
  int hi = lane >> 4;

  f16x8 bf[4][4];
#pragma unroll
  for (int kk = 0; kk < 4; ++kk) {
    int kbase = kk * 32 + hi * 8;
#pragma unroll
    for (int t = 0; t < 4; ++t) bf[kk][t] = ldB(W, kbase, t * 16 + lo);
  }

  f32x4 acc[4];
#pragma unroll
  for (int t = 0; t < 4; ++t) acc[t] = (f32x4){0.f, 0.f, 0.f, 0.f};

  const float* xr = x + (size_t)(r0 + lo) * DIN;
#pragma unroll
  for (int kk = 0; kk < 4; ++kk) {
    int kbase = kk * 32 + hi * 8;
    float4 xa = *(const float4*)(xr + kbase);
    float4 xb = *(const float4*)(xr + kbase + 4);
    f16x8 af;
    af[0] = (_Float16)xa.x; af[1] = (_Float16)xa.y;
    af[2] = (_Float16)xa.z; af[3] = (_Float16)xa.w;
    af[4] = (_Float16)xb.x; af[5] = (_Float16)xb.y;
    af[6] = (_Float16)xb.z; af[7] = (_Float16)xb.w;
#pragma unroll
    for (int t = 0; t < 4; ++t)
      acc[t] = __builtin_amdgcn_mfma_f32_16x16x32_f16(af, bf[kk][t], acc[t], 0, 0, 0);
  }

  float bc[4], lsv[4], lbv[4];
#pragma unroll
  for (int t = 0; t < 4; ++t) {
    int c = t * 16 + lo;
    bc[t] = b[c]; lsv[t] = s[c]; lbv[t] = beta[c];
  }
#pragma unroll
  for (int reg = 0; reg < 4; ++reg) {
    float v[4];
    float s1 = 0.0f;
#pragma unroll
    for (int t = 0; t < 4; ++t) { v[t] = acc[t][reg] + bc[t]; s1 += v[t]; }
#pragma unroll
    for (int off = 1; off < 16; off <<= 1) s1 += __shfl_xor(s1, off);
    float m = s1 * (1.0f / 64.0f);
    float s2 = 0.0f;
#pragma unroll
    for (int t = 0; t < 4; ++t) { float d = v[t] - m; s2 += d * d; }
#pragma unroll
    for (int off = 1; off < 16; off <<= 1) s2 += __shfl_xor(s2, off);
    float rinv = rsqrtf(s2 * (1.0f / 64.0f) + LN_EPS);
    int r = r0 + hi * 4 + reg;
#pragma unroll
    for (int t = 0; t < 4; ++t) {
      float o = (v[t] - m) * rinv * lsv[t] + lbv[t];
      y[(size_t)r * D + t * 16 + lo] = __float2half(fmaxf(o, 0.0f));
    }
  }
}

// =============== atomic-free CSR build: 2-level counting sort ===============
// R1: int4-vectorized per-block LDS histogram of bucket (= key>>10).
// EPB and all region boundaries are multiples of 4 -> 4-chunks never straddle
// regions and never cross E_ALL partially.
__global__ __launch_bounds__(256) void r1_hist_kernel(
    const int* __restrict__ ei_gg, const int* __restrict__ ei_cg,
    const int* __restrict__ ei_cc, int* __restrict__ bhist,
    int* __restrict__ btot) {
  __shared__ int hist[256];
  int t = threadIdx.x;
  int k = blockIdx.x;
  hist[t] = 0;
  __syncthreads();
  int base = k * EPB;
  for (int i = t * 4; i < EPB; i += 1024) {
    int e = base + i;
    if (e >= E_ALL) break;
    int4 d4; int off;
    if (e < EGG) { d4 = *(const int4*)&ei_gg[EGG + e]; off = 0; }
    else if (e < EGG + ECG) { d4 = *(const int4*)&ei_cg[ECG + (e - EGG)]; off = NG; }
    else { d4 = *(const int4*)&ei_cc[ECC + (e - EGG - ECG)]; off = 2 * NG; }
    atomicAdd(&hist[(d4.x + off) >> 10], 1);
    atomicAdd(&hist[(d4.y + off) >> 10], 1);
    atomicAdd(&hist[(d4.z + off) >> 10], 1);
    atomicAdd(&hist[(d4.w + off) >> 10], 1);
  }
  __syncthreads();
  if (t < NBKT) {
    bhist[t * NBLK + k] = hist[t];
    atomicAdd(&btot[t], hist[t]);
  }
}

__global__ __launch_bounds__(256) void r2b_kernel(
    const int* __restrict__ btot, int* __restrict__ bbase,
    int* __restrict__ S) {
  __shared__ int sh[256];
  int t = threadIdx.x;
  int v = (t < NBKT) ? btot[t] : 0;
  sh[t] = v;
  __syncthreads();
#pragma unroll
  for (int off = 1; off < 256; off <<= 1) {
    int u = (t >= off) ? sh[t - off] : 0;
    __syncthreads();
    sh[t] += u;
    __syncthreads();
  }
  if (t < NBKT) bbase[t] = sh[t] - v;
  if (t == 255) { bbase[NBKT] = sh[255]; S[SCAN_N] = sh[255]; }
}

__global__ __launch_bounds__(512) void r2c_kernel(
    const int* __restrict__ bhist, const int* __restrict__ bbase,
    int* __restrict__ base) {
  int b = blockIdx.x;
  int t = threadIdx.x;
  int lane = t & 63, wv = t >> 6;
  int v = bhist[b * NBLK + t];
  int sc = v;
#pragma unroll
  for (int off = 1; off < 64; off <<= 1) {
    int u = __shfl_up(sc, off);
    if (lane >= off) sc += u;
  }
  __shared__ int ws[8];
  if (lane == 63) ws[wv] = sc;
  __syncthreads();
  int wb = 0;
  for (int i = 0; i < wv; ++i) wb += ws[i];
  base[b * NBLK + t] = bbase[b] + wb + sc - v;
}

// R3: int4-vectorized scatter of packed (localkey<<17 | src) records.
__global__ __launch_bounds__(256) void r3_scatter_kernel(
    const int* __restrict__ ei_gg, const float* __restrict__ ew_gg,
    const int* __restrict__ ei_cg, const int* __restrict__ ei_cc,
    const int* __restrict__ base, int* __restrict__ ssort,
    float* __restrict__ wsort) {
  __shared__ int cur[256];
  int t = threadIdx.x;
  int k = blockIdx.x;
  if (t < NBKT) cur[t] = base[t * NBLK + k];
  __syncthreads();
  int bb = k * EPB;
  for (int i = t * 4; i < EPB; i += 1024) {
    int e = bb + i;
    if (e >= E_ALL) break;
    int4 d4, s4; float4 w4; int off; bool isg = false;
    if (e < EGG) {
      d4 = *(const int4*)&ei_gg[EGG + e];
      s4 = *(const int4*)&ei_gg[e];
      w4 = *(const float4*)&ew_gg[e];
      off = 0; isg = true;
    } else if (e < EGG + ECG) {
      int q = e - EGG;
      d4 = *(const int4*)&ei_cg[ECG + q];
      s4 = *(const int4*)&ei_cg[q];
      off = NG;
    } else {
      int q = e - EGG - ECG;
      d4 = *(const int4*)&ei_cc[ECC + q];
      s4 = *(const int4*)&ei_cc[q];
      off = 2 * NG;
    }
    int keys[4] = {d4.x + off, d4.y + off, d4.z + off, d4.w + off};
    int srcs[4] = {s4.x, s4.y, s4.z, s4.w};
    float ws4[4] = {w4.x, w4.y, w4.z, w4.w};
#pragma unroll
    for (int j = 0; j < 4; ++j) {
      int p = atomicAdd(&cur[keys[j] >> 10], 1);   // LDS atomic
      ssort[p] = ((keys[j] & 1023) << 17) | srcs[j];
      if (isg) wsort[p] = ws4[j];
    }
  }
}

// R4: per-bucket 1024-bin counting sort; also folds the weighted-degree
// accumulation (dinv = rsqrt(1 + sum_w)) for gg keys via LDS float atomics.
__global__ __launch_bounds__(1024) void r4_sort_kernel(
    const int* __restrict__ ssort, const float* __restrict__ wsort,
    const int* __restrict__ bbase, int* __restrict__ S,
    int* __restrict__ srcbuf, float* __restrict__ ewp,
    float* __restrict__ dinv) {
  int b = blockIdx.x;
  int t = threadIdx.x;
  int e0 = bbase[b], e1 = bbase[b + 1];
  int kbase = b << 10;
  __shared__ int hist[1024];
  __shared__ int sh[1024];
  __shared__ int cur[1024];
  __shared__ float wsum[1024];
  hist[t] = 0;
  wsum[t] = 0.0f;
  __syncthreads();
  for (int e = e0 + t; e < e1; e += 1024)
    atomicAdd(&hist[((unsigned)ssort[e]) >> 17], 1);
  __syncthreads();
  int c = hist[t];
  sh[t] = c;
  __syncthreads();
#pragma unroll
  for (int off = 1; off < 1024; off <<= 1) {
    int u = (t >= off) ? sh[t - off] : 0;
    __syncthreads();
    sh[t] += u;
    __syncthreads();
  }
  int ex = e0 + sh[t] - c;
  int key = kbase + t;
  if (key < SCAN_N) S[key] = ex;
  cur[t] = ex;
  __syncthreads();
  for (int e = e0 + t; e < e1; e += 1024) {
    int rec = ssort[e];
    int lk = ((unsigned)rec) >> 17;
    int p = atomicAdd(&cur[lk], 1);
    srcbuf[p] = rec & 0x1FFFF;
    if (kbase + lk < NG) {
      float w = wsort[e];
      ewp[p] = w;
      atomicAdd(&wsum[lk], w);
    }
  }
  __syncthreads();
  if (key < NG) dinv[key] = rsqrtf(wsum[t] + 1.0f);
}

__global__ __launch_bounds__(256) void nrm_kernel(
    const int* __restrict__ S, const int* __restrict__ srcbuf,
    const float* __restrict__ ewp, const float* __restrict__ dinv,
    float* __restrict__ nrm) {
  int i = (int)(((size_t)blockIdx.x * blockDim.x + threadIdx.x) >> 6);
  int lane = threadIdx.x & 63;
  if (i >= NG) return;
  float di = dinv[i];
  int e0 = S[i], e1 = S[i + 1];
  for (int e = e0 + lane; e < e1; e += 64)
    nrm[e] = dinv[srcbuf[e]] * ewp[e] * di;
}

// ---------------- fused glom layer: 16 rows/block, MFMA epilogue ------------
__global__ __launch_bounds__(1024) void glom_layer_kernel(
    const int* __restrict__ rp_gg, const int* __restrict__ rp_cg,
    const int* __restrict__ srcbuf, const float* __restrict__ nrm_gg,
    const __half* __restrict__ xg_old, const __half* __restrict__ xc_old,
    const float* __restrict__ dinv,
    const float* __restrict__ W_gcn, const float* __restrict__ b_gcn,
    const float* __restrict__ eps_cg, const float* __restrict__ W_cg,
    const float* __restrict__ b_cg,
    const float* __restrict__ ls, const float* __restrict__ lb,
    __half* __restrict__ xg_new) {
  __shared__ __align__(16) _Float16 A1[16][72];
  __shared__ __align__(16) _Float16 A2[16][72];
  int wv = threadIdx.x >> 6;
  int lane = threadIdx.x & 63;
  int iu = __builtin_amdgcn_readfirstlane(blockIdx.x * 16 + wv);

  int ge0 = __builtin_amdgcn_readfirstlane(rp_gg[iu]);
  int ge1 = __builtin_amdgcn_readfirstlane(rp_gg[iu + 1]);
  int fe0 = __builtin_amdgcn_readfirstlane(rp_cg[iu]);
  int fe1 = __builtin_amdgcn_readfirstlane(rp_cg[iu + 1]);
  float self = __half2float(xg_old[(size_t)iu * D + lane]);
  float di = dinv[iu];
  float accG = di * di * self
             + csr_gather_s2(srcbuf, nrm_gg, xg_old, ge0, ge1, lane);
  float accC = csr_gather_s2(srcbuf, nullptr, xc_old, fe0, fe1, lane);
  float h = (1.0f + eps_cg[0]) * self + accC;
  A1[wv][lane] = (_Float16)accG;
  A2[wv][lane] = (_Float16)h;
  __syncthreads();
  if (wv != 0) return;

  int lo = lane & 15;
  int hi = lane >> 4;
  f16x8 a1[2], a2[2];
#pragma unroll
  for (int kk = 0; kk < 2; ++kk) {
    a1[kk] = *(const f16x8*)&A1[lo][kk * 32 + hi * 8];
    a2[kk] = *(const f16x8*)&A2[lo][kk * 32 + hi * 8];
  }
  f32x4 c1[4], c2[4];
#pragma unroll
  for (int t = 0; t < 4; ++t) {
    int c = t * 16 + lo;
    f32x4 acc = (f32x4){0.f, 0.f, 0.f, 0.f};
#pragma unroll
    for (int kk = 0; kk < 2; ++kk)
      acc = __builtin_amdgcn_mfma_f32_16x16x32_f16(a1[kk], ldB(W_gcn, kk * 32 + hi * 8, c), acc, 0, 0, 0);
    c1[t] = acc;
    acc = (f32x4){0.f, 0.f, 0.f, 0.f};
#pragma unroll
    for (int kk = 0; kk < 2; ++kk)
      acc = __builtin_amdgcn_mfma_f32_16x16x32_f16(a2[kk], ldB(W_cg, kk * 32 + hi * 8, c), acc, 0, 0, 0);
    c2[t] = acc;
  }
  float bc1[4], bc2[4], lsv[4], lbv[4];
#pragma unroll
  for (int t = 0; t < 4; ++t) {
    int c = t * 16 + lo;
    bc1[t] = b_gcn[c]; bc2[t] = b_cg[c]; lsv[t] = ls[c]; lbv[t] = lb[c];
  }
#pragma unroll
  for (int reg = 0; reg < 4; ++reg) {
    float v[4];
    float s1 = 0.0f;
#pragma unroll
    for (int t = 0; t < 4; ++t) {
      v[t] = (c1[t][reg] + bc1[t]) + fmaxf(c2[t][reg] + bc2[t], 0.0f);
      s1 += v[t];
    }
#pragma unroll
    for (int off = 1; off < 16; off <<= 1) s1 += __shfl_xor(s1, off);
    float m = s1 * (1.0f / 64.0f);
    float s2 = 0.0f;
#pragma unroll
    for (int t = 0; t < 4; ++t) { float d = v[t] - m; s2 += d * d; }
#pragma unroll
    for (int off = 1; off < 16; off <<= 1) s2 += __shfl_xor(s2, off);
    float rinv = rsqrtf(s2 * (1.0f / 64.0f) + LN_EPS);
    int r = blockIdx.x * 16 + hi * 4 + reg;
#pragma unroll
    for (int t = 0; t < 4; ++t) {
      float o = (v[t] - m) * rinv * lsv[t] + lbv[t];
      xg_new[(size_t)r * D + t * 16 + lo] = __float2half(fmaxf(o, 0.0f));
    }
  }
}

// ---------------- fused cell layer: 16 rows/block, MFMA epilogue ------------
__global__ __launch_bounds__(1024) void cell_layer_kernel(
    const int* __restrict__ rp_cc, const int* __restrict__ srcbuf,
    const __half* __restrict__ xc_old,
    const float* __restrict__ eps_cc, const float* __restrict__ W_cc,
    const float* __restrict__ b_cc,
    const float* __restrict__ ls, const float* __restrict__ lb,
    __half* __restrict__ xc_new) {
  __shared__ __align__(16) _Float16 A2[16][72];
  int wv = threadIdx.x >> 6;
  int lane = threadIdx.x & 63;
  int iu = __builtin_amdgcn_readfirstlane(blockIdx.x * 16 + wv);

  int e0 = __builtin_amdgcn_readfirstlane(rp_cc[iu]);
  int e1 = __builtin_amdgcn_readfirstlane(rp_cc[iu + 1]);
  float self = __half2float(xc_old[(size_t)iu * D + lane]);
  float acc = csr_gather_s2(srcbuf, nullptr, xc_old, e0, e1, lane);
  float h = (1.0f + eps_cc[0]) * self + acc;
  A2[wv][lane] = (_Float16)h;
  __syncthreads();
  if (wv != 0) return;

  int lo = lane & 15;
  int hi = lane >> 4;
  f16x8 a2[2];
#pragma unroll
  for (int kk = 0; kk < 2; ++kk)
    a2[kk] = *(const f16x8*)&A2[lo][kk * 32 + hi * 8];
  f32x4 c2[4];
#pragma unroll
  for (int t = 0; t < 4; ++t) {
    int c = t * 16 + lo;
    f32x4 a = (f32x4){0.f, 0.f, 0.f, 0.f};
#pragma unroll
    for (int kk = 0; kk < 2; ++kk)
      a = __builtin_amdgcn_mfma_f32_16x16x32_f16(a2[kk], ldB(W_cc, kk * 32 + hi * 8, c), a, 0, 0, 0);
    c2[t] = a;
  }
  float bc2[4], lsv[4], lbv[4];
#pragma unroll
  for (int t = 0; t < 4; ++t) {
    int c = t * 16 + lo;
    bc2[t] = b_cc[c]; lsv[t] = ls[c]; lbv[t] = lb[c];
  }
#pragma unroll
  for (int reg = 0; reg < 4; ++reg) {
    float v[4];
    float s1 = 0.0f;
#pragma unroll
    for (int t = 0; t < 4; ++t) {
      v[t] = fmaxf(c2[t][reg] + bc2[t], 0.0f);
      s1 += v[t];
    }
#pragma unroll
    for (int off = 1; off < 16; off <<= 1) s1 += __shfl_xor(s1, off);
    float m = s1 * (1.0f / 64.0f);
    float s2 = 0.0f;
#pragma unroll
    for (int t = 0; t < 4; ++t) { float d = v[t] - m; s2 += d * d; }
#pragma unroll
    for (int off = 1; off < 16; off <<= 1) s2 += __shfl_xor(s2, off);
    float rinv = rsqrtf(s2 * (1.0f / 64.0f) + LN_EPS);
    int r = blockIdx.x * 16 + hi * 4 + reg;
#pragma unroll
    for (int t = 0; t < 4; ++t) {
      float o = (v[t] - m) * rinv * lsv[t] + lbv[t];
      xc_new[(size_t)r * D + t * 16 + lo] = __float2half(fmaxf(o, 0.0f));
    }
  }
}

// ---------------- output head: wave per row --------------------------------
__global__ __launch_bounds__(256) void out_kernel(
    const __half* __restrict__ xg, const float* __restrict__ W,
    const float* __restrict__ b, float* __restrict__ out, int n) {
  int wid = (int)(((size_t)blockIdx.x * blockDim.x + threadIdx.x) >> 6);
  int lane = threadIdx.x & 63;
  if (wid >= n) return;
  float v = __half2float(xg[(size_t)wid * D + lane]);
  float a0 = wave_sum64(v * W[lane * 3 + 0]) + b[0];
  float a1 = wave_sum64(v * W[lane * 3 + 1]) + b[1];
  float a2 = wave_sum64(v * W[lane * 3 + 2]) + b[2];
  float m = fmaxf(a0, fmaxf(a1, a2));
  float e0 = expf(a0 - m), e1 = expf(a1 - m), e2 = expf(a2 - m);
  float inv = 1.0f / (e0 + e1 + e2);
  if (lane == 0) {
    out[(size_t)wid * 3 + 0] = e0 * inv;
    out[(size_t)wid * 3 + 1] = e1 * inv;
    out[(size_t)wid * 3 + 2] = e2 * inv;
  }
}

extern "C" void kernel_launch(void* const* d_in, const int* in_sizes, int n_in,
                              void* d_out, int out_size, void* d_ws, size_t ws_size,
                              hipStream_t stream) {
  const float* x_glom = (const float*)d_in[0];
  const float* x_cell = (const float*)d_in[1];
  const int*   ei_gg  = (const int*)d_in[2];
  const float* ew_gg  = (const float*)d_in[3];
  const int*   ei_cg  = (const int*)d_in[4];
  const int*   ei_cc  = (const int*)d_in[5];
  const float* W_in_g = (const float*)d_in[6];
  const float* b_in_g = (const float*)d_in[7];
  const float* lnig_s = (const float*)d_in[8];
  const float* lnig_b = (const float*)d_in[9];
  const float* W_in_c = (const float*)d_in[10];
  const float* b_in_c = (const float*)d_in[11];
  const float* lnic_s = (const float*)d_in[12];
  const float* lnic_b = (const float*)d_in[13];
  const float* W_outp = (const float*)d_in[34];
  const float* b_outp = (const float*)d_in[35];

  // ---- workspace layout ----
  char* P = (char*)d_ws;
  __half* xg0 = (__half*)P;                    P += (size_t)NG * D * 2;
  __half* xg1 = (__half*)P;                    P += (size_t)NG * D * 2;
  __half* xc0 = (__half*)P;                    P += (size_t)NC * D * 2;
  __half* xc1 = (__half*)P;                    P += (size_t)NC * D * 2;
  float* dinv = (float*)P;                     P += (size_t)NG * 4;
  float* nrm  = (float*)P;                     P += (size_t)EGG * 4;
  int* S      = (int*)P;                       P += (size_t)(SCAN_N + 1) * 4;
  int* srcbuf = (int*)P;                       P += (size_t)E_ALL * 4;
  int* bhist  = (int*)P;                       P += (size_t)NBKT * NBLK * 4;
  int* base   = (int*)P;                       P += (size_t)NBKT * NBLK * 4;
  int* btot   = (int*)P;                       P += (size_t)NBKT * 4;
  int* bbase  = (int*)P;                       P += (size_t)(NBKT + 1) * 4;
  // transients over the feature-table region (dead before fc_in writes it)
  int* ssort   = (int*)d_ws;
  float* wsort = (float*)(ssort + E_ALL);
  float* ewp   = wsort + EGG;

  dim3 blk(256);
  auto wgrid = [](long long waves) { return dim3((unsigned)((waves + 3) / 4)); };

  // ---- CSR build: atomic-free two-level counting sort ----
  hipMemsetAsync(btot, 0, NBKT * sizeof(int), stream);
  r1_hist_kernel<<<dim3(NBLK), blk, 0, stream>>>(ei_gg, ei_cg, ei_cc, bhist, btot);
  r2b_kernel<<<dim3(1), dim3(256), 0, stream>>>(btot, bbase, S);
  r2c_kernel<<<dim3(NBKT), dim3(512), 0, stream>>>(bhist, bbase, base);
  r3_scatter_kernel<<<dim3(NBLK), blk, 0, stream>>>(
      ei_gg, ew_gg, ei_cg, ei_cc, base, ssort, wsort);
  r4_sort_kernel<<<dim3(NBKT), dim3(1024), 0, stream>>>(
      ssort, wsort, bbase, S, srcbuf, ewp, dinv);
  nrm_kernel<<<wgrid(NG), blk, 0, stream>>>(S, srcbuf, ewp, dinv, nrm);

  // ---- input FCs via MFMA (overwrite the transient ssort/wsort/ewp region) --
  fc_in_mfma_kernel<<<wgrid(NG / 16), blk, 0, stream>>>(
      x_glom, W_in_g, b_in_g, lnig_s, lnig_b, xg0, NG);
  fc_in_mfma_kernel<<<wgrid(NC / 16), blk, 0, stream>>>(
      x_cell, W_in_c, b_in_c, lnic_s, lnic_b, xc0, NC);

  // ---- two hetero MP layers (16 rows/block, MFMA epilogue) ----
  const int* rp_gg = S;
  const int* rp_cg = S + NG;
  const int* rp_cc = S + 2 * NG;
  __half* xg_cur = xg0; __half* xg_nxt = xg1;
  __half* xc_cur = xc0; __half* xc_nxt = xc1;
  for (int l = 0; l < 2; ++l) {
    const float* const* p = (const float* const*)(d_in + 14 + 10 * l);
    const float* W_gcn = p[0]; const float* b_gcn = p[1];
    const float* eps_cg = p[2]; const float* W_cg = p[3]; const float* b_cg = p[4];
    const float* eps_cc = p[5]; const float* W_cc = p[6]; const float* b_cc = p[7];
    const float* ln_s = p[8]; const float* ln_b = p[9];

    glom_layer_kernel<<<dim3(NG / 16), dim3(1024), 0, stream>>>(
        rp_gg, rp_cg, srcbuf, nrm, xg_cur, xc_cur, dinv,
        W_gcn, b_gcn, eps_cg, W_cg, b_cg, ln_s, ln_b, xg_nxt);
    cell_layer_kernel<<<dim3(NC / 16), dim3(1024), 0, stream>>>(
        rp_cc, srcbuf, xc_cur, eps_cc, W_cc, b_cc, ln_s, ln_b, xc_nxt);

    __half* t;
    t = xg_cur; xg_cur = xg_nxt; xg_nxt = t;
    t = xc_cur; xc_cur = xc_nxt; xc_nxt = t;
  }

  out_kernel<<<wgrid(NG), blk, 0, stream>>>(xg_cur, W_outp, b_outp, (float*)d_out, NG);
}

// Round 17
// 457.386 us; speedup vs baseline: 1.0382x; 1.0005x over previous
//
#include <hip/hip_runtime.h>
#include <hip/hip_fp16.h>

#define NG 50000
#define NC 100000
#define DIN 128
#define D 64
#define EGG 800000
#define ECG 1600000
#define ECC 1600000
#define LN_EPS 1e-5f

#define SCAN_N (2 * NG + NC)            // 200000 keys: gg dst | cg dst | cc dst
#define E_ALL (EGG + ECG + ECC)         // 4,000,000 edges
#define NBKT 196                        // buckets of 1024 keys
#define NBLK 512                        // blocks in R1/R3
#define EPB 7816                        // edges per block (4-aligned; 512*7816 >= E_ALL)

typedef _Float16 f16x8 __attribute__((ext_vector_type(8)));
typedef float f32x4 __attribute__((ext_vector_type(4)));

__device__ __forceinline__ float wave_sum64(float v) {
#pragma unroll
  for (int off = 32; off > 0; off >>= 1) v += __shfl_xor(v, off);
  return v;
}

// ---- pair-edge scalar-indexed fp16 CSR gather -------------------------------
__device__ __forceinline__ float csr_gather_s2(
    const int* __restrict__ src, const float* __restrict__ nrm,
    const __half* __restrict__ tab, int e0, int e1, int lane) {
  int h = lane >> 5;
  int m = lane & 31;
  float ax0 = 0.f, ax1 = 0.f, ax2 = 0.f, ax3 = 0.f;
  float ay0 = 0.f, ay1 = 0.f, ay2 = 0.f, ay3 = 0.f;
  for (int e = e0; e < e1; e += 16) {
#pragma unroll
    for (int p = 0; p < 8; ++p) {
      int i0 = e + 2 * p;
      int se = src[i0];
      int so = src[i0 + 1];
      int s = h ? so : se;
      bool valid = (i0 + h) < e1;
      float w;
      if (nrm) {
        float we = nrm[i0], wo = nrm[i0 + 1];
        w = h ? wo : we;
      } else {
        w = 1.0f;
      }
      w = valid ? w : 0.0f;
      s = valid ? s : 0;
      __half2 v = *(const __half2*)(tab + (size_t)s * D + 2 * m);
      float vl = __low2float(v), vh = __high2float(v);
      switch (p & 3) {
        case 0: ax0 = fmaf(w, vl, ax0); ay0 = fmaf(w, vh, ay0); break;
        case 1: ax1 = fmaf(w, vl, ax1); ay1 = fmaf(w, vh, ay1); break;
        case 2: ax2 = fmaf(w, vl, ax2); ay2 = fmaf(w, vh, ay2); break;
        default: ax3 = fmaf(w, vl, ax3); ay3 = fmaf(w, vh, ay3); break;
      }
    }
  }
  float ax = (ax0 + ax1) + (ax2 + ax3);
  float ay = (ay0 + ay1) + (ay2 + ay3);
  ax += __shfl_xor(ax, 32);
  ay += __shfl_xor(ay, 32);
  float ev = __shfl(ax, lane >> 1);
  float od = __shfl(ay, lane >> 1);
  return (lane & 1) ? od : ev;
}

// B-fragment loader: W fp32 [64][64] -> f16x8 frag (col c, k = kbase..kbase+7)
__device__ __forceinline__ f16x8 ldB(const float* __restrict__ W, int kbase, int c) {
  f16x8 v;
#pragma unroll
  for (int j = 0; j < 8; ++j) v[j] = (_Float16)W[(kbase + j) * 64 + c];
  return v;
}

// ---------------- dense input FC via MFMA -----------------------------------
__global__ __launch_bounds__(256) void fc_in_mfma_kernel(
    const float* __restrict__ x, const float* __restrict__ W,
    const float* __restrict__ b, const float* __restrict__ s,
    const float* __restrict__ beta, __half* __restrict__ y, int n) {
  int wid = (int)(((size_t)blockIdx.x * blockDim.x + threadIdx.x) >> 6);
  int lane = threadIdx.x & 63;
  int r0 = wid * 16;
  if (r0 >= n) return;
  int lo = lane & 15;
  int hi = lane >> 4;

  f16x8 bf[4][4];
#pragma unroll
  for (int kk = 0; kk < 4; ++kk) {
    int kbase = kk * 32 + hi * 8;
#pragma unroll
    for (int t = 0; t < 4; ++t) bf[kk][t] = ldB(W, kbase, t * 16 + lo);
  }

  f32x4 acc[4];
#pragma unroll
  for (int t = 0; t < 4; ++t) acc[t] = (f32x4){0.f, 0.f, 0.f, 0.f};

  const float* xr = x + (size_t)(r0 + lo) * DIN;
#pragma unroll
  for (int kk = 0; kk < 4; ++kk) {
    int kbase = kk * 32 + hi * 8;
    float4 xa = *(const float4*)(xr + kbase);
    float4 xb = *(const float4*)(xr + kbase + 4);
    f16x8 af;
    af[0] = (_Float16)xa.x; af[1] = (_Float16)xa.y;
    af[2] = (_Float16)xa.z; af[3] = (_Float16)xa.w;
    af[4] = (_Float16)xb.x; af[5] = (_Float16)xb.y;
    af[6] = (_Float16)xb.z; af[7] = (_Float16)xb.w;
#pragma unroll
    for (int t = 0; t < 4; ++t)
      acc[t] = __builtin_amdgcn_mfma_f32_16x16x32_f16(af, bf[kk][t], acc[t], 0, 0, 0);
  }

  float bc[4], lsv[4], lbv[4];
#pragma unroll
  for (int t = 0; t < 4; ++t) {
    int c = t * 16 + lo;
    bc[t] = b[c]; lsv[t] = s[c]; lbv[t] = beta[c];
  }
#pragma unroll
  for (int reg = 0; reg < 4; ++reg) {
    float v[4];
    float s1 = 0.0f;
#pragma unroll
    for (int t = 0; t < 4; ++t) { v[t] = acc[t][reg] + bc[t]; s1 += v[t]; }
#pragma unroll
    for (int off = 1; off < 16; off <<= 1) s1 += __shfl_xor(s1, off);
    float m = s1 * (1.0f / 64.0f);
    float s2 = 0.0f;
#pragma unroll
    for (int t = 0; t < 4; ++t) { float d = v[t] - m; s2 += d * d; }
#pragma unroll
    for (int off = 1; off < 16; off <<= 1) s2 += __shfl_xor(s2, off);
    float rinv = rsqrtf(s2 * (1.0f / 64.0f) + LN_EPS);
    int r = r0 + hi * 4 + reg;
#pragma unroll
    for (int t = 0; t < 4; ++t) {
      float o = (v[t] - m) * rinv * lsv[t] + lbv[t];
      y[(size_t)r * D + t * 16 + lo] = __float2half(fmaxf(o, 0.0f));
    }
  }
}

// =============== atomic-free CSR build: 2-level counting sort ===============
__global__ __launch_bounds__(256) void r1_hist_kernel(
    const int* __restrict__ ei_gg, const int* __restrict__ ei_cg,
    const int* __restrict__ ei_cc, int* __restrict__ bhist,
    int* __restrict__ btot) {
  __shared__ int hist[256];
  int t = threadIdx.x;
  int k = blockIdx.x;
  hist[t] = 0;
  __syncthreads();
  int base = k * EPB;
  for (int i = t * 4; i < EPB; i += 1024) {
    int e = base + i;
    if (e >= E_ALL) break;
    int4 d4; int off;
    if (e < EGG) { d4 = *(const int4*)&ei_gg[EGG + e]; off = 0; }
    else if (e < EGG + ECG) { d4 = *(const int4*)&ei_cg[ECG + (e - EGG)]; off = NG; }
    else { d4 = *(const int4*)&ei_cc[ECC + (e - EGG - ECG)]; off = 2 * NG; }
    atomicAdd(&hist[(d4.x + off) >> 10], 1);
    atomicAdd(&hist[(d4.y + off) >> 10], 1);
    atomicAdd(&hist[(d4.z + off) >> 10], 1);
    atomicAdd(&hist[(d4.w + off) >> 10], 1);
  }
  __syncthreads();
  if (t < NBKT) {
    bhist[t * NBLK + k] = hist[t];
    atomicAdd(&btot[t], hist[t]);
  }
}

__global__ __launch_bounds__(256) void r2b_kernel(
    const int* __restrict__ btot, int* __restrict__ bbase,
    int* __restrict__ S) {
  __shared__ int sh[256];
  int t = threadIdx.x;
  int v = (t < NBKT) ? btot[t] : 0;
  sh[t] = v;
  __syncthreads();
#pragma unroll
  for (int off = 1; off < 256; off <<= 1) {
    int u = (t >= off) ? sh[t - off] : 0;
    __syncthreads();
    sh[t] += u;
    __syncthreads();
  }
  if (t < NBKT) bbase[t] = sh[t] - v;
  if (t == 255) { bbase[NBKT] = sh[255]; S[SCAN_N] = sh[255]; }
}

__global__ __launch_bounds__(512) void r2c_kernel(
    const int* __restrict__ bhist, const int* __restrict__ bbase,
    int* __restrict__ base) {
  int b = blockIdx.x;
  int t = threadIdx.x;
  int lane = t & 63, wv = t >> 6;
  int v = bhist[b * NBLK + t];
  int sc = v;
#pragma unroll
  for (int off = 1; off < 64; off <<= 1) {
    int u = __shfl_up(sc, off);
    if (lane >= off) sc += u;
  }
  __shared__ int ws[8];
  if (lane == 63) ws[wv] = sc;
  __syncthreads();
  int wb = 0;
  for (int i = 0; i < wv; ++i) wb += ws[i];
  base[b * NBLK + t] = bbase[b] + wb + sc - v;
}

// R3: int4-vectorized scatter of packed (localkey<<17 | src) records.
__global__ __launch_bounds__(256) void r3_scatter_kernel(
    const int* __restrict__ ei_gg, const float* __restrict__ ew_gg,
    const int* __restrict__ ei_cg, const int* __restrict__ ei_cc,
    const int* __restrict__ base, int* __restrict__ ssort,
    float* __restrict__ wsort) {
  __shared__ int cur[256];
  int t = threadIdx.x;
  int k = blockIdx.x;
  if (t < NBKT) cur[t] = base[t * NBLK + k];
  __syncthreads();
  int bb = k * EPB;
  for (int i = t * 4; i < EPB; i += 1024) {
    int e = bb + i;
    if (e >= E_ALL) break;
    int4 d4, s4; float4 w4; int off; bool isg = false;
    if (e < EGG) {
      d4 = *(const int4*)&ei_gg[EGG + e];
      s4 = *(const int4*)&ei_gg[e];
      w4 = *(const float4*)&ew_gg[e];
      off = 0; isg = true;
    } else if (e < EGG + ECG) {
      int q = e - EGG;
      d4 = *(const int4*)&ei_cg[ECG + q];
      s4 = *(const int4*)&ei_cg[q];
      off = NG;
    } else {
      int q = e - EGG - ECG;
      d4 = *(const int4*)&ei_cc[ECC + q];
      s4 = *(const int4*)&ei_cc[q];
      off = 2 * NG;
    }
    int keys[4] = {d4.x + off, d4.y + off, d4.z + off, d4.w + off};
    int srcs[4] = {s4.x, s4.y, s4.z, s4.w};
    float ws4[4] = {w4.x, w4.y, w4.z, w4.w};
#pragma unroll
    for (int j = 0; j < 4; ++j) {
      int p = atomicAdd(&cur[keys[j] >> 10], 1);   // LDS atomic
      ssort[p] = ((keys[j] & 1023) << 17) | srcs[j];
      if (isg) wsort[p] = ws4[j];
    }
  }
}

// R4: per-bucket 1024-bin counting sort (hierarchical wave scan, 2 barriers
// instead of 20) + folded weighted-degree -> dinv for gg keys.
__global__ __launch_bounds__(1024) void r4_sort_kernel(
    const int* __restrict__ ssort, const float* __restrict__ wsort,
    const int* __restrict__ bbase, int* __restrict__ S,
    int* __restrict__ srcbuf, float* __restrict__ ewp,
    float* __restrict__ dinv) {
  int b = blockIdx.x;
  int t = threadIdx.x;
  int lane = t & 63;
  int wv = t >> 6;
  int e0 = bbase[b], e1 = bbase[b + 1];
  int kbase = b << 10;
  __shared__ int hist[1024];
  __shared__ int cur[1024];
  __shared__ float wsum[1024];
  __shared__ int wsums[16];
  hist[t] = 0;
  wsum[t] = 0.0f;
  __syncthreads();
  for (int e = e0 + t; e < e1; e += 1024)
    atomicAdd(&hist[((unsigned)ssort[e]) >> 17], 1);
  __syncthreads();
  int c = hist[t];
  // hierarchical exclusive scan: wave-level shfl scan + wave-sum combine
  int sc = c;
#pragma unroll
  for (int off = 1; off < 64; off <<= 1) {
    int u = __shfl_up(sc, off);
    if (lane >= off) sc += u;
  }
  if (lane == 63) wsums[wv] = sc;
  __syncthreads();
  int wbase = 0;
#pragma unroll
  for (int i = 0; i < 16; ++i) wbase += (i < wv) ? wsums[i] : 0;
  int ex = e0 + wbase + sc - c;    // global exclusive prefix for key kbase+t
  int key = kbase + t;
  if (key < SCAN_N) S[key] = ex;
  cur[t] = ex;
  __syncthreads();
  for (int e = e0 + t; e < e1; e += 1024) {
    int rec = ssort[e];
    int lk = ((unsigned)rec) >> 17;
    int p = atomicAdd(&cur[lk], 1);
    srcbuf[p] = rec & 0x1FFFF;
    if (kbase + lk < NG) {
      float w = wsort[e];
      ewp[p] = w;
      atomicAdd(&wsum[lk], w);
    }
  }
  __syncthreads();
  if (key < NG) dinv[key] = rsqrtf(wsum[t] + 1.0f);
}

__global__ __launch_bounds__(256) void nrm_kernel(
    const int* __restrict__ S, const int* __restrict__ srcbuf,
    const float* __restrict__ ewp, const float* __restrict__ dinv,
    float* __restrict__ nrm) {
  int i = (int)(((size_t)blockIdx.x * blockDim.x + threadIdx.x) >> 6);
  int lane = threadIdx.x & 63;
  if (i >= NG) return;
  float di = dinv[i];
  int e0 = S[i], e1 = S[i + 1];
  for (int e = e0 + lane; e < e1; e += 64)
    nrm[e] = dinv[srcbuf[e]] * ewp[e] * di;
}

// ---------------- fused glom layer: 16 rows/block, MFMA epilogue ------------
__global__ __launch_bounds__(1024) void glom_layer_kernel(
    const int* __restrict__ rp_gg, const int* __restrict__ rp_cg,
    const int* __restrict__ srcbuf, const float* __restrict__ nrm_gg,
    const __half* __restrict__ xg_old, const __half* __restrict__ xc_old,
    const float* __restrict__ dinv,
    const float* __restrict__ W_gcn, const float* __restrict__ b_gcn,
    const float* __restrict__ eps_cg, const float* __restrict__ W_cg,
    const float* __restrict__ b_cg,
    const float* __restrict__ ls, const float* __restrict__ lb,
    __half* __restrict__ xg_new) {
  __shared__ __align__(16) _Float16 A1[16][72];
  __shared__ __align__(16) _Float16 A2[16][72];
  int wv = threadIdx.x >> 6;
  int lane = threadIdx.x & 63;
  int iu = __builtin_amdgcn_readfirstlane(blockIdx.x * 16 + wv);

  int ge0 = __builtin_amdgcn_readfirstlane(rp_gg[iu]);
  int ge1 = __builtin_amdgcn_readfirstlane(rp_gg[iu + 1]);
  int fe0 = __builtin_amdgcn_readfirstlane(rp_cg[iu]);
  int fe1 = __builtin_amdgcn_readfirstlane(rp_cg[iu + 1]);
  float self = __half2float(xg_old[(size_t)iu * D + lane]);
  float di = dinv[iu];
  float accG = di * di * self
             + csr_gather_s2(srcbuf, nrm_gg, xg_old, ge0, ge1, lane);
  float accC = csr_gather_s2(srcbuf, nullptr, xc_old, fe0, fe1, lane);
  float h = (1.0f + eps_cg[0]) * self + accC;
  A1[wv][lane] = (_Float16)accG;
  A2[wv][lane] = (_Float16)h;
  __syncthreads();
  if (wv != 0) return;

  int lo = lane & 15;
  int hi = lane >> 4;
  f16x8 a1[2], a2[2];
#pragma unroll
  for (int kk = 0; kk < 2; ++kk) {
    a1[kk] = *(const f16x8*)&A1[lo][kk * 32 + hi * 8];
    a2[kk] = *(const f16x8*)&A2[lo][kk * 32 + hi * 8];
  }
  f32x4 c1[4], c2[4];
#pragma unroll
  for (int t = 0; t < 4; ++t) {
    int c = t * 16 + lo;
    f32x4 acc = (f32x4){0.f, 0.f, 0.f, 0.f};
#pragma unroll
    for (int kk = 0; kk < 2; ++kk)
      acc = __builtin_amdgcn_mfma_f32_16x16x32_f16(a1[kk], ldB(W_gcn, kk * 32 + hi * 8, c), acc, 0, 0, 0);
    c1[t] = acc;
    acc = (f32x4){0.f, 0.f, 0.f, 0.f};
#pragma unroll
    for (int kk = 0; kk < 2; ++kk)
      acc = __builtin_amdgcn_mfma_f32_16x16x32_f16(a2[kk], ldB(W_cg, kk * 32 + hi * 8, c), acc, 0, 0, 0);
    c2[t] = acc;
  }
  float bc1[4], bc2[4], lsv[4], lbv[4];
#pragma unroll
  for (int t = 0; t < 4; ++t) {
    int c = t * 16 + lo;
    bc1[t] = b_gcn[c]; bc2[t] = b_cg[c]; lsv[t] = ls[c]; lbv[t] = lb[c];
  }
#pragma unroll
  for (int reg = 0; reg < 4; ++reg) {
    float v[4];
    float s1 = 0.0f;
#pragma unroll
    for (int t = 0; t < 4; ++t) {
      v[t] = (c1[t][reg] + bc1[t]) + fmaxf(c2[t][reg] + bc2[t], 0.0f);
      s1 += v[t];
    }
#pragma unroll
    for (int off = 1; off < 16; off <<= 1) s1 += __shfl_xor(s1, off);
    float m = s1 * (1.0f / 64.0f);
    float s2 = 0.0f;
#pragma unroll
    for (int t = 0; t < 4; ++t) { float d = v[t] - m; s2 += d * d; }
#pragma unroll
    for (int off = 1; off < 16; off <<= 1) s2 += __shfl_xor(s2, off);
    float rinv = rsqrtf(s2 * (1.0f / 64.0f) + LN_EPS);
    int r = blockIdx.x * 16 + hi * 4 + reg;
#pragma unroll
    for (int t = 0; t < 4; ++t) {
      float o = (v[t] - m) * rinv * lsv[t] + lbv[t];
      xg_new[(size_t)r * D + t * 16 + lo] = __float2half(fmaxf(o, 0.0f));
    }
  }
}

// ---------------- fused cell layer: 16 rows/block, MFMA epilogue ------------
__global__ __launch_bounds__(1024) void cell_layer_kernel(
    const int* __restrict__ rp_cc, const int* __restrict__ srcbuf,
    const __half* __restrict__ xc_old,
    const float* __restrict__ eps_cc, const float* __restrict__ W_cc,
    const float* __restrict__ b_cc,
    const float* __restrict__ ls, const float* __restrict__ lb,
    __half* __restrict__ xc_new) {
  __shared__ __align__(16) _Float16 A2[16][72];
  int wv = threadIdx.x >> 6;
  int lane = threadIdx.x & 63;
  int iu = __builtin_amdgcn_readfirstlane(blockIdx.x * 16 + wv);

  int e0 = __builtin_amdgcn_readfirstlane(rp_cc[iu]);
  int e1 = __builtin_amdgcn_readfirstlane(rp_cc[iu + 1]);
  float self = __half2float(xc_old[(size_t)iu * D + lane]);
  float acc = csr_gather_s2(srcbuf, nullptr, xc_old, e0, e1, lane);
  float h = (1.0f + eps_cc[0]) * self + acc;
  A2[wv][lane] = (_Float16)h;
  __syncthreads();
  if (wv != 0) return;

  int lo = lane & 15;
  int hi = lane >> 4;
  f16x8 a2[2];
#pragma unroll
  for (int kk = 0; kk < 2; ++kk)
    a2[kk] = *(const f16x8*)&A2[lo][kk * 32 + hi * 8];
  f32x4 c2[4];
#pragma unroll
  for (int t = 0; t < 4; ++t) {
    int c = t * 16 + lo;
    f32x4 a = (f32x4){0.f, 0.f, 0.f, 0.f};
#pragma unroll
    for (int kk = 0; kk < 2; ++kk)
      a = __builtin_amdgcn_mfma_f32_16x16x32_f16(a2[kk], ldB(W_cc, kk * 32 + hi * 8, c), a, 0, 0, 0);
    c2[t] = a;
  }
  float bc2[4], lsv[4], lbv[4];
#pragma unroll
  for (int t = 0; t < 4; ++t) {
    int c = t * 16 + lo;
    bc2[t] = b_cc[c]; lsv[t] = ls[c]; lbv[t] = lb[c];
  }
#pragma unroll
  for (int reg = 0; reg < 4; ++reg) {
    float v[4];
    float s1 = 0.0f;
#pragma unroll
    for (int t = 0; t < 4; ++t) {
      v[t] = fmaxf(c2[t][reg] + bc2[t], 0.0f);
      s1 += v[t];
    }
#pragma unroll
    for (int off = 1; off < 16; off <<= 1) s1 += __shfl_xor(s1, off);
    float m = s1 * (1.0f / 64.0f);
    float s2 = 0.0f;
#pragma unroll
    for (int t = 0; t < 4; ++t) { float d = v[t] - m; s2 += d * d; }
#pragma unroll
    for (int off = 1; off < 16; off <<= 1) s2 += __shfl_xor(s2, off);
    float rinv = rsqrtf(s2 * (1.0f / 64.0f) + LN_EPS);
    int r = blockIdx.x * 16 + hi * 4 + reg;
#pragma unroll
    for (int t = 0; t < 4; ++t) {
      float o = (v[t] - m) * rinv * lsv[t] + lbv[t];
      xc_new[(size_t)r * D + t * 16 + lo] = __float2half(fmaxf(o, 0.0f));
    }
  }
}

// ---------------- output head: wave per row --------------------------------
__global__ __launch_bounds__(256) void out_kernel(
    const __half* __restrict__ xg, const float* __restrict__ W,
    const float* __restrict__ b, float* __restrict__ out, int n) {
  int wid = (int)(((size_t)blockIdx.x * blockDim.x + threadIdx.x) >> 6);
  int lane = threadIdx.x & 63;
  if (wid >= n) return;
  float v = __half2float(xg[(size_t)wid * D + lane]);
  float a0 = wave_sum64(v * W[lane * 3 + 0]) + b[0];
  float a1 = wave_sum64(v * W[lane * 3 + 1]) + b[1];
  float a2 = wave_sum64(v * W[lane * 3 + 2]) + b[2];
  float m = fmaxf(a0, fmaxf(a1, a2));
  float e0 = expf(a0 - m), e1 = expf(a1 - m), e2 = expf(a2 - m);
  float inv = 1.0f / (e0 + e1 + e2);
  if (lane == 0) {
    out[(size_t)wid * 3 + 0] = e0 * inv;
    out[(size_t)wid * 3 + 1] = e1 * inv;
    out[(size_t)wid * 3 + 2] = e2 * inv;
  }
}

extern "C" void kernel_launch(void* const* d_in, const int* in_sizes, int n_in,
                              void* d_out, int out_size, void* d_ws, size_t ws_size,
                              hipStream_t stream) {
  const float* x_glom = (const float*)d_in[0];
  const float* x_cell = (const float*)d_in[1];
  const int*   ei_gg  = (const int*)d_in[2];
  const float* ew_gg  = (const float*)d_in[3];
  const int*   ei_cg  = (const int*)d_in[4];
  const int*   ei_cc  = (const int*)d_in[5];
  const float* W_in_g = (const float*)d_in[6];
  const float* b_in_g = (const float*)d_in[7];
  const float* lnig_s = (const float*)d_in[8];
  const float* lnig_b = (const float*)d_in[9];
  const float* W_in_c = (const float*)d_in[10];
  const float* b_in_c = (const float*)d_in[11];
  const float* lnic_s = (const float*)d_in[12];
  const float* lnic_b = (const float*)d_in[13];
  const float* W_outp = (const float*)d_in[34];
  const float* b_outp = (const float*)d_in[35];

  // ---- workspace layout ----
  char* P = (char*)d_ws;
  __half* xg0 = (__half*)P;                    P += (size_t)NG * D * 2;
  __half* xg1 = (__half*)P;                    P += (size_t)NG * D * 2;
  __half* xc0 = (__half*)P;                    P += (size_t)NC * D * 2;
  __half* xc1 = (__half*)P;                    P += (size_t)NC * D * 2;
  float* dinv = (float*)P;                     P += (size_t)NG * 4;
  float* nrm  = (float*)P;                     P += (size_t)EGG * 4;
  int* S      = (int*)P;                       P += (size_t)(SCAN_N + 1) * 4;
  int* srcbuf = (int*)P;                       P += (size_t)E_ALL * 4;
  int* bhist  = (int*)P;                       P += (size_t)NBKT * NBLK * 4;
  int* base   = (int*)P;                       P += (size_t)NBKT * NBLK * 4;
  int* btot   = (int*)P;                       P += (size_t)NBKT * 4;
  int* bbase  = (int*)P;                       P += (size_t)(NBKT + 1) * 4;
  // transients over the feature-table region (dead before fc_in writes it)
  int* ssort   = (int*)d_ws;
  float* wsort = (float*)(ssort + E_ALL);
  float* ewp   = wsort + EGG;

  dim3 blk(256);
  auto wgrid = [](long long waves) { return dim3((unsigned)((waves + 3) / 4)); };

  // ---- CSR build: atomic-free two-level counting sort ----
  hipMemsetAsync(btot, 0, NBKT * sizeof(int), stream);
  r1_hist_kernel<<<dim3(NBLK), blk, 0, stream>>>(ei_gg, ei_cg, ei_cc, bhist, btot);
  r2b_kernel<<<dim3(1), dim3(256), 0, stream>>>(btot, bbase, S);
  r2c_kernel<<<dim3(NBKT), dim3(512), 0, stream>>>(bhist, bbase, base);
  r3_scatter_kernel<<<dim3(NBLK), blk, 0, stream>>>(
      ei_gg, ew_gg, ei_cg, ei_cc, base, ssort, wsort);
  r4_sort_kernel<<<dim3(NBKT), dim3(1024), 0, stream>>>(
      ssort, wsort, bbase, S, srcbuf, ewp, dinv);
  nrm_kernel<<<wgrid(NG), blk, 0, stream>>>(S, srcbuf, ewp, dinv, nrm);

  // ---- input FCs via MFMA (overwrite the transient ssort/wsort/ewp region) --
  fc_in_mfma_kernel<<<wgrid(NG / 16), blk, 0, stream>>>(
      x_glom, W_in_g, b_in_g, lnig_s, lnig_b, xg0, NG);
  fc_in_mfma_kernel<<<wgrid(NC / 16), blk, 0, stream>>>(
      x_cell, W_in_c, b_in_c, lnic_s, lnic_b, xc0, NC);

  // ---- two hetero MP layers (16 rows/block, MFMA epilogue) ----
  const int* rp_gg = S;
  const int* rp_cg = S + NG;
  const int* rp_cc = S + 2 * NG;
  __half* xg_cur = xg0; __half* xg_nxt = xg1;
  __half* xc_cur = xc0; __half* xc_nxt = xc1;
  for (int l = 0; l < 2; ++l) {
    const float* const* p = (const float* const*)(d_in + 14 + 10 * l);
    const float* W_gcn = p[0]; const float* b_gcn = p[1];
    const float* eps_cg = p[2]; const float* W_cg = p[3]; const float* b_cg = p[4];
    const float* eps_cc = p[5]; const float* W_cc = p[6]; const float* b_cc = p[7];
    const float* ln_s = p[8]; const float* ln_b = p[9];

    glom_layer_kernel<<<dim3(NG / 16), dim3(1024), 0, stream>>>(
        rp_gg, rp_cg, srcbuf, nrm, xg_cur, xc_cur, dinv,
        W_gcn, b_gcn, eps_cg, W_cg, b_cg, ln_s, ln_b, xg_nxt);
    cell_layer_kernel<<<dim3(NC / 16), dim3(1024), 0, stream>>>(
        rp_cc, srcbuf, xc_cur, eps_cc, W_cc, b_cc, ln_s, ln_b, xc_nxt);

    __half* t;
    t = xg_cur; xg_cur = xg_nxt; xg_nxt = t;
    t = xc_cur; xc_cur = xc_nxt; xc_nxt = t;
  }

  out_kernel<<<wgrid(NG), blk, 0, stream>>>(xg_cur, W_outp, b_outp, (float*)d_out, NG);
}